// Round 2
// baseline (33407.489 us; speedup 1.0000x reference)
//
#include <hip/hip_runtime.h>
#include <math.h>

// Problem dims (fixed by the reference)
#define BB 64
#define TT 1024
#define EE 256
#define HH 512
#define OO 32000
#define KDIM 768   // H+E

typedef float f32x2 __attribute__((ext_vector_type(2)));

__device__ __forceinline__ f32x2 mk2(float a, float b) { f32x2 r; r.x = a; r.y = b; return r; }

#if __has_builtin(__builtin_elementwise_fma)
#define FMA2(a, b, c) __builtin_elementwise_fma((a), (b), (c))
#else
__device__ __forceinline__ f32x2 FMA2(f32x2 a, f32x2 b, f32x2 c) {
  c.x = fmaf(a.x, b.x, c.x); c.y = fmaf(a.y, b.y, c.y); return c;
}
#endif

// ---------------------------------------------------------------------------
// Recurrence kernel: one block per batch element, 1024 threads (16 waves),
// exactly one block resident per CU (launch_bounds(1024,4) -> VGPR cap 512).
// Thread tid = kg*64 + jl:
//   kg = wave index 0..15  -> owns k-range [kg*48, kg*48+48)  of combined [h;e]
//   jl = lane  index 0..63 -> owns j-range [jl*8,  jl*8+8)    of hidden outputs
// Weights (8 j x 48 k = 384 f32) are pinned in VGPRs for the whole T loop via
// keep-alive volatile asm (the compiler otherwise sinks the loads into the
// loop and re-streams 98 GB of weights -- round-1 failure mode).
// All 64 lanes of a wave read the SAME combined[k] slice -> LDS broadcast.
// Partials reduced across the 16 waves through LDS.
// ---------------------------------------------------------------------------
__global__ __launch_bounds__(1024, 4) void rnn_kernel(
    const int* __restrict__ x, const float* __restrict__ hidden0,
    const float* __restrict__ emb, const float* __restrict__ Wi,
    const float* __restrict__ bi, float* __restrict__ hid_out)
{
  __shared__ float4 comb4[KDIM / 4];       // [0..127] = h, [128..191] = e
  __shared__ float4 part4[16 * HH / 4];    // part[16][512]
  __shared__ int xrow[TT];
  float* comb = (float*)comb4;
  float* part = (float*)part4;

  const int b   = blockIdx.x;
  const int tid = threadIdx.x;
  const int kg  = tid >> 6;
  const int jl  = tid & 63;

  // init: x row into LDS, h(0) into comb
  xrow[tid] = x[b * TT + tid];
  if (tid < HH) comb[tid] = hidden0[b * HH + tid];
  __syncthreads();

  const float4* emb4 = (const float4*)emb;
  // e(0) (padding_idx = 0 -> zeros)
  if (kg == 8) {
    int idx = xrow[0];
    float4 e0 = make_float4(0.f, 0.f, 0.f, 0.f);
    if (idx != 0) e0 = emb4[idx * (EE / 4) + jl];
    comb4[HH / 4 + jl] = e0;
  }

  // preload this thread's weight tile into registers: w2[jj][pair over 48 k]
  f32x2 w2[8][24];
  {
    const float4* Wi4 = (const float4*)Wi;
    #pragma unroll
    for (int jj = 0; jj < 8; ++jj) {
      const int row = jl * 8 + jj;
      const float4* wr = Wi4 + (row * KDIM + kg * 48) / 4;
      #pragma unroll
      for (int q = 0; q < 12; ++q) {
        float4 v = wr[q];
        w2[jj][q * 2 + 0] = mk2(v.x, v.y);
        w2[jj][q * 2 + 1] = mk2(v.z, v.w);
      }
    }
  }
  // Pin the weight tile into VGPRs: volatile asm outputs cannot be
  // rematerialized, so the allocator must keep all 384 floats resident
  // instead of re-loading them from global inside the t-loop.
  #pragma unroll
  for (int jj = 0; jj < 8; ++jj) {
    #pragma unroll
    for (int q = 0; q < 24; ++q) {
      asm volatile("" : "+v"(w2[jj][q]));
    }
  }

  const float bj = (tid < HH) ? bi[tid] : 0.0f;
  __syncthreads();

  #pragma unroll 1
  for (int t = 0; t < TT; ++t) {
    // ---------------- phase 1: dot-products + e(t+1) prefetch ----------------
    float4 e4 = make_float4(0.f, 0.f, 0.f, 0.f);
    if (kg == 8 && t + 1 < TT) {
      int idx = xrow[t + 1];
      if (idx != 0) e4 = emb4[idx * (EE / 4) + jl];   // latency hidden under FMAs
    }

    f32x2 acc[8];
    #pragma unroll
    for (int jj = 0; jj < 8; ++jj) acc[jj] = mk2(0.f, 0.f);

    const float4* c4 = comb4 + kg * 12;   // this wave's 48-float slice (broadcast)
    #pragma unroll
    for (int c = 0; c < 4; ++c) {
      float4 h0 = c4[c * 3 + 0];
      float4 h1 = c4[c * 3 + 1];
      float4 h2 = c4[c * 3 + 2];
      f32x2 hh0 = mk2(h0.x, h0.y), hh1 = mk2(h0.z, h0.w);
      f32x2 hh2 = mk2(h1.x, h1.y), hh3 = mk2(h1.z, h1.w);
      f32x2 hh4 = mk2(h2.x, h2.y), hh5 = mk2(h2.z, h2.w);
      #pragma unroll
      for (int jj = 0; jj < 8; ++jj) {
        acc[jj] = FMA2(w2[jj][c * 6 + 0], hh0, acc[jj]);
        acc[jj] = FMA2(w2[jj][c * 6 + 1], hh1, acc[jj]);
        acc[jj] = FMA2(w2[jj][c * 6 + 2], hh2, acc[jj]);
        acc[jj] = FMA2(w2[jj][c * 6 + 3], hh3, acc[jj]);
        acc[jj] = FMA2(w2[jj][c * 6 + 4], hh4, acc[jj]);
        acc[jj] = FMA2(w2[jj][c * 6 + 5], hh5, acc[jj]);
      }
    }

    // write 8 partial sums (two float4 stores) into part[kg][jl*8 .. jl*8+7]
    float4 p0 = make_float4(acc[0].x + acc[0].y, acc[1].x + acc[1].y,
                            acc[2].x + acc[2].y, acc[3].x + acc[3].y);
    float4 p1 = make_float4(acc[4].x + acc[4].y, acc[5].x + acc[5].y,
                            acc[6].x + acc[6].y, acc[7].x + acc[7].y);
    part4[kg * 128 + jl * 2 + 0] = p0;
    part4[kg * 128 + jl * 2 + 1] = p1;
    __syncthreads();

    // ---------------- phase 2: reduce across waves, tanh, update comb -------
    if (tid < HH) {
      float s = bj;
      #pragma unroll
      for (int g = 0; g < 16; ++g) s += part[g * HH + tid];
      comb[tid] = tanhf(s);
    }
    if (kg == 8 && t + 1 < TT) comb4[HH / 4 + jl] = e4;
    __syncthreads();
  }

  if (tid < HH) hid_out[b * HH + tid] = comb[tid];
}

// ---------------------------------------------------------------------------
// Decoder: out[b][o] = sum_j h[b][j] * W_dec[o][j] + b_dec[o]
// grid (125, 2): 256 o-columns per block, 32 batch rows per block.
// h tile staged in LDS [32][512] f32 (64 KB), read as float4 broadcasts.
// ---------------------------------------------------------------------------
__global__ __launch_bounds__(256) void dec_kernel(
    const float* __restrict__ hid, const float* __restrict__ Wd,
    const float* __restrict__ bd, float* __restrict__ out)
{
  __shared__ float4 hl4[32 * 128];   // [bb][j4] — contiguous copy of hid[b0..b0+32)
  const int o  = blockIdx.x * 256 + threadIdx.x;
  const int b0 = blockIdx.y * 32;

  const float4* hid4 = (const float4*)(hid + b0 * HH);
  #pragma unroll
  for (int i = 0; i < 16; ++i) {
    int lin = i * 256 + threadIdx.x;
    hl4[lin] = hid4[lin];
  }
  __syncthreads();

  f32x2 acc[32];
  #pragma unroll
  for (int bb = 0; bb < 32; ++bb) acc[bb] = mk2(0.f, 0.f);

  const float4* W4 = (const float4*)(Wd + (size_t)o * HH);
  for (int j4 = 0; j4 < 128; ++j4) {
    float4 w = W4[j4];
    f32x2 wa = mk2(w.x, w.y), wb = mk2(w.z, w.w);
    #pragma unroll
    for (int bb = 0; bb < 32; ++bb) {
      float4 h = hl4[bb * 128 + j4];
      acc[bb] = FMA2(wa, mk2(h.x, h.y), acc[bb]);
      acc[bb] = FMA2(wb, mk2(h.z, h.w), acc[bb]);
    }
  }

  const float bias = bd[o];
  #pragma unroll
  for (int bb = 0; bb < 32; ++bb)
    out[(size_t)(b0 + bb) * OO + o] = acc[bb].x + acc[bb].y + bias;
}

// ---------------------------------------------------------------------------
extern "C" void kernel_launch(void* const* d_in, const int* in_sizes, int n_in,
                              void* d_out, int out_size, void* d_ws, size_t ws_size,
                              hipStream_t stream) {
  const int*   x    = (const int*)  d_in[0];   // [64][1024] int32
  const float* hid0 = (const float*)d_in[1];   // [64][512]
  const float* emb  = (const float*)d_in[2];   // [32000][256]
  const float* Wi   = (const float*)d_in[3];   // [512][768]
  const float* bi   = (const float*)d_in[4];   // [512]
  const float* Wd   = (const float*)d_in[5];   // [32000][512]
  const float* bd   = (const float*)d_in[6];   // [32000]

  float* out     = (float*)d_out;              // [64][32000] output
  float* hid_out = out + (size_t)BB * OO;      // [64][512] final hidden

  rnn_kernel<<<BB, 1024, 0, stream>>>(x, hid0, emb, Wi, bi, hid_out);
  dec_kernel<<<dim3(OO / 256, BB / 32), 256, 0, stream>>>(hid_out, Wd, bd, out);
}

// Round 3
// 8166.635 us; speedup vs baseline: 4.0907x; 4.0907x over previous
//
#include <hip/hip_runtime.h>
#include <math.h>

// Problem dims (fixed by the reference)
#define BB 64
#define TT 1024
#define EE 256
#define HH 512
#define OO 32000
#define KDIM 768   // H+E
#define NS 4       // CU-slices per batch row; 256 blocks total = 256 CUs

typedef float f32x2 __attribute__((ext_vector_type(2)));

__device__ __forceinline__ f32x2 mk2(float a, float b) { f32x2 r; r.x = a; r.y = b; return r; }

#if __has_builtin(__builtin_elementwise_fma)
#define FMA2(a, b, c) __builtin_elementwise_fma((a), (b), (c))
#else
__device__ __forceinline__ f32x2 FMA2(f32x2 a, f32x2 b, f32x2 c) {
  c.x = fmaf(a.x, b.x, c.x); c.y = fmaf(a.y, b.y, c.y); return c;
}
#endif

#define REP24(M) M(0) M(1) M(2) M(3) M(4) M(5) M(6) M(7) M(8) M(9) M(10) M(11) \
                 M(12) M(13) M(14) M(15) M(16) M(17) M(18) M(19) M(20) M(21) M(22) M(23)

// Weight tile: 24 float4 = 96 floats per thread, held as 48 NAMED f32x2 scalars
// (no array -> no alloca -> cannot be demoted to scratch; r286 rule #20).
#define WLOAD(q) float4 v##q = wrow[q]; \
                 f32x2 wa##q = mk2(v##q.x, v##q.y), wb##q = mk2(v##q.z, v##q.w);
#define WPIN(q)  asm volatile("" : "+v"(wa##q), "+v"(wb##q));
#define WFMA(q)  { float4 c = cq[q]; \
                   acc0 = FMA2(wa##q, mk2(c.x, c.y), acc0); \
                   acc1 = FMA2(wb##q, mk2(c.z, c.w), acc1); }

// ---------------------------------------------------------------------------
// Recurrence: grid = 256 blocks (= #CUs, 1 block/CU at VGPR<=128), 1024 thr.
// Block bid -> (b = bid>>2, s = bid&3): owns output rows j in [128s,128s+128),
// full k = 768. Thread tid -> (kg = tid>>7 in [0,8), jj = tid&127):
// weights W[128s+jj][96kg .. 96kg+96) in registers; all lanes of a wave share
// kg -> comb reads are wave-uniform ds_read_b128 broadcasts (conflict-free).
// Per-step h exchange between the 4 sibling blocks via agent-scope atomics
// (release/acquire -> wbl2/inv, coherent across XCDs through IF$).
// ---------------------------------------------------------------------------
__global__ __launch_bounds__(1024, 4) void rnn_kernel(
    const int* __restrict__ x, const float* __restrict__ hidden0,
    const float* __restrict__ emb, const float* __restrict__ Wi,
    const float* __restrict__ bi, float* __restrict__ hid_out,
    float* __restrict__ hbuf, unsigned int* __restrict__ cnt)
{
  __shared__ float4 comb4[KDIM / 4];   // [0..127]=h (global j order), [128..191]=e
  __shared__ float part[8 * 128];      // partials [kg][jj]
  __shared__ int xrow[TT];
  float* comb = (float*)comb4;

  const int bid = blockIdx.x;
  const int b = bid >> 2, s = bid & 3;
  const int tid = threadIdx.x;
  const int jj = tid & 127;
  const int kg = tid >> 7;

  xrow[tid] = x[b * TT + tid];
  if (tid < 128) comb4[tid] = ((const float4*)hidden0)[b * 128 + tid];
  __syncthreads();   // xrow ready

  const float4* emb4 = (const float4*)emb;
  if (tid >= 896 && tid < 960) {       // e(0); padding_idx=0 -> zeros
    int idx = xrow[0];
    float4 e0 = make_float4(0.f, 0.f, 0.f, 0.f);
    if (idx != 0) e0 = emb4[idx * (EE / 4) + (tid - 896)];
    comb4[128 + (tid - 896)] = e0;
  }

  // weight preload: row = 128s+jj, cols [96kg, 96kg+96)
  const float4* wrow = (const float4*)Wi + (size_t)(s * 128 + jj) * (KDIM / 4) + kg * 24;
  REP24(WLOAD)
  REP24(WPIN)
  const float bias = (tid < 128) ? bi[s * 128 + tid] : 0.0f;
  __syncthreads();   // comb(0) ready

  float4* hb4 = (float4*)hbuf;               // [2][64][128] float4
  unsigned int* mycnt = cnt + b * 4;         // slots t&3, accumulating targets

  #pragma unroll 1
  for (int i = 0; i < TT; ++i) {
    // prefetch e(i+1) (latency hides under FMAs)
    float4 e4 = make_float4(0.f, 0.f, 0.f, 0.f);
    const int doe = (tid >= 896 && tid < 960 && i + 1 < TT);
    if (doe) {
      int idx = xrow[i + 1];
      if (idx != 0) e4 = emb4[idx * (EE / 4) + (tid - 896)];
    }

    // ---- dot: 96 MACs/thread, weights in regs, comb via LDS broadcast ----
    f32x2 acc0 = mk2(0.f, 0.f), acc1 = mk2(0.f, 0.f);
    const float4* cq = comb4 + kg * 24;
    REP24(WFMA)
    part[kg * 128 + jj] = acc0.x + acc0.y + acc1.x + acc1.y;
    __syncthreads();

    // ---- reduce over 8 kg-groups, tanh, own slice into comb ----
    float h = 0.0f;
    if (tid < 128) {
      float ssum = bias;
      #pragma unroll
      for (int g = 0; g < 8; ++g) ssum += part[g * 128 + tid];
      h = tanhf(ssum);
      comb[s * 128 + tid] = h;
    }

    if (i != TT - 1) {
      const int buf = (i + 1) & 1;
      if (tid < 128) hbuf[(size_t)(buf * BB + b) * HH + s * 128 + tid] = h;
      __syncthreads();   // publish stores drained (per-wave vmcnt at barrier)

      if (tid == 0) {
        __hip_atomic_fetch_add(&mycnt[i & 3], 1u, __ATOMIC_RELEASE,
                               __HIP_MEMORY_SCOPE_AGENT);
        const unsigned target = 4u * ((unsigned)(i >> 2) + 1u);
        while (__hip_atomic_load(&mycnt[i & 3], __ATOMIC_RELAXED,
                                 __HIP_MEMORY_SCOPE_AGENT) < target)
          __builtin_amdgcn_s_sleep(1);
        (void)__hip_atomic_load(&mycnt[i & 3], __ATOMIC_ACQUIRE,
                                __HIP_MEMORY_SCOPE_AGENT);   // inv L1/L2
      }
      __syncthreads();

      // read the 3 foreign slices (384 floats) from IF$-fresh hbuf
      if (tid < 96) {
        int idx4 = tid + ((tid >= s * 32) ? 32 : 0);   // skip own 32 float4
        comb4[idx4] = hb4[(size_t)(buf * BB + b) * 128 + idx4];
      }
      if (doe) comb4[128 + (tid - 896)] = e4;
      __syncthreads();
    } else {
      if (tid < 128) hid_out[b * HH + s * 128 + tid] = h;
    }
  }
}

// ---------------------------------------------------------------------------
// Decoder: out[b][o] = sum_j h[b][j] * W_dec[o][j] + b_dec[o]
// ---------------------------------------------------------------------------
__global__ __launch_bounds__(256) void dec_kernel(
    const float* __restrict__ hid, const float* __restrict__ Wd,
    const float* __restrict__ bd, float* __restrict__ out)
{
  __shared__ float4 hl4[32 * 128];
  const int o  = blockIdx.x * 256 + threadIdx.x;
  const int b0 = blockIdx.y * 32;

  const float4* hid4 = (const float4*)(hid + b0 * HH);
  #pragma unroll
  for (int i = 0; i < 16; ++i) {
    int lin = i * 256 + threadIdx.x;
    hl4[lin] = hid4[lin];
  }
  __syncthreads();

  f32x2 acc[32];
  #pragma unroll
  for (int bb = 0; bb < 32; ++bb) acc[bb] = mk2(0.f, 0.f);

  const float4* W4 = (const float4*)(Wd + (size_t)o * HH);
  for (int j4 = 0; j4 < 128; ++j4) {
    float4 w = W4[j4];
    f32x2 wa = mk2(w.x, w.y), wb = mk2(w.z, w.w);
    #pragma unroll
    for (int bb = 0; bb < 32; ++bb) {
      float4 h = hl4[bb * 128 + j4];
      acc[bb] = FMA2(wa, mk2(h.x, h.y), acc[bb]);
      acc[bb] = FMA2(wb, mk2(h.z, h.w), acc[bb]);
    }
  }

  const float bias = bd[o];
  #pragma unroll
  for (int bb = 0; bb < 32; ++bb)
    out[(size_t)(b0 + bb) * OO + o] = acc[bb].x + acc[bb].y + bias;
}

// ---------------------------------------------------------------------------
extern "C" void kernel_launch(void* const* d_in, const int* in_sizes, int n_in,
                              void* d_out, int out_size, void* d_ws, size_t ws_size,
                              hipStream_t stream) {
  const int*   x    = (const int*)  d_in[0];   // [64][1024] int32
  const float* hid0 = (const float*)d_in[1];   // [64][512]
  const float* emb  = (const float*)d_in[2];   // [32000][256]
  const float* Wi   = (const float*)d_in[3];   // [512][768]
  const float* bi   = (const float*)d_in[4];   // [512]
  const float* Wd   = (const float*)d_in[5];   // [32000][512]
  const float* bd   = (const float*)d_in[6];   // [32000]

  float* out     = (float*)d_out;              // [64][32000]
  float* hid_out = out + (size_t)BB * OO;      // [64][512] final hidden

  unsigned int* cnt = (unsigned int*)d_ws;                 // [64][4] counters
  float* hbuf = (float*)((char*)d_ws + 4096);              // [2][64][512] f32

  // zero the sync counters every launch (poison/replay-safe; capture-legal)
  hipMemsetAsync(d_ws, 0, 64 * 4 * sizeof(unsigned int), stream);

  rnn_kernel<<<BB * NS, 1024, 0, stream>>>(x, hid0, emb, Wi, bi, hid_out, hbuf, cnt);
  dec_kernel<<<dim3(OO / 256, BB / 32), 256, 0, stream>>>(hid_out, Wd, bd, out);
}

// Round 4
// 2215.690 us; speedup vs baseline: 15.0777x; 3.6858x over previous
//
#include <hip/hip_runtime.h>
#include <math.h>

// Problem dims (fixed by the reference)
#define BB 64
#define TT 1024
#define EE 256
#define HH 512
#define OO 32000
#define KDIM 768   // H+E

typedef float f32x2 __attribute__((ext_vector_type(2)));

__device__ __forceinline__ f32x2 mk2(float a, float b) { f32x2 r; r.x = a; r.y = b; return r; }

#if __has_builtin(__builtin_elementwise_fma)
#define FMA2(a, b, c) __builtin_elementwise_fma((a), (b), (c))
#else
__device__ __forceinline__ f32x2 FMA2(f32x2 a, f32x2 b, f32x2 c) {
  c.x = fmaf(a.x, b.x, c.x); c.y = fmaf(a.y, b.y, c.y); return c;
}
#endif

// fast tanh on the critical reduce path: tanh(x) = (e^2x - 1)/(e^2x + 1)
// v_exp_f32 computes 2^x, so t = 2^(2*log2(e)*x). Clamp so t never overflows.
__device__ __forceinline__ float fast_tanh(float x) {
  float xc = fminf(fmaxf(x, -10.0f), 10.0f);
  float e;
  asm("v_exp_f32 %0, %1" : "=v"(e) : "v"(xc * 2.885390081777927f)); // 2*log2(e)
  float r;
  asm("v_rcp_f32 %0, %1" : "=v"(r) : "v"(e + 1.0f));
  return (e - 1.0f) * r;
}

// Weight tile: 4 j-rows x 24 k = 96 floats per thread, held as 48 NAMED f32x2
// scalars (no array -> no alloca -> cannot be demoted to scratch).
#define FORQ(M, J) M(J,0) M(J,1) M(J,2) M(J,3) M(J,4) M(J,5)
#define FORALL(M) FORQ(M,0) FORQ(M,1) FORQ(M,2) FORQ(M,3)

#define WLOAD(J,Q) float4 v##J##_##Q = wr##J[Q]; \
  f32x2 wa##J##_##Q = mk2(v##J##_##Q.x, v##J##_##Q.y); \
  f32x2 wb##J##_##Q = mk2(v##J##_##Q.z, v##J##_##Q.w);
#define WPIN(J,Q) asm volatile("" : "+v"(wa##J##_##Q), "+v"(wb##J##_##Q));
#define WFMA(J,Q) acc##J = FMA2(wa##J##_##Q, mk2(cc##Q.x, cc##Q.y), acc##J); \
                  acc##J = FMA2(wb##J##_##Q, mk2(cc##Q.z, cc##Q.w), acc##J);
#define CHUNK1(J) WFMA(J,0) WFMA(J,1) WFMA(J,2)
#define CHUNK2(J) WFMA(J,3) WFMA(J,4) WFMA(J,5)

// ---------------------------------------------------------------------------
// Recurrence: 256 blocks (1/CU), 1024 threads. Block bid -> b = bid&63,
// s = bid>>6 (all 4 siblings of a row land on XCD b%8). Block owns output
// rows j in [128s, 128s+128), all k. Thread: jo = tid&31 (4 j-rows
// 128s+4jo..+3), kg = tid>>5 (k-slice [24kg, 24kg+24)).
// Cross-block h exchange per step: RELAXED agent-scope atomics only (sc0 sc1,
// straight to IF$) — NO release/acquire, so no buffer_wbl2 / buffer_inv per
// step (the round-3 17.5k-cycle step cost). Ordering: publish stores ->
// s_waitcnt vmcnt(0) -> counter fetch_add; readers spin on counter then read.
// ---------------------------------------------------------------------------
__global__ __launch_bounds__(1024, 4) void rnn_kernel(
    const int* __restrict__ x, const float* __restrict__ hidden0,
    const float* __restrict__ emb, const float* __restrict__ Wi,
    const float* __restrict__ bi, float* __restrict__ hid_out,
    float* __restrict__ hbuf, unsigned int* __restrict__ cnt)
{
  __shared__ float4 comb4[KDIM / 4];     // [0..127]=h (global j), [128..191]=e
  __shared__ float4 part4[32 * 32];      // partials [kg=32][j=128] as float4
  __shared__ int xrow[TT];
  float* comb = (float*)comb4;
  float* part = (float*)part4;

  const int bid = blockIdx.x;
  const int b = bid & 63, s = bid >> 6;
  const int tid = threadIdx.x;
  const int jo = tid & 31;    // j-group of 4
  const int kg = tid >> 5;    // 0..31

  xrow[tid] = x[b * TT + tid];
  if (tid < 128) comb4[tid] = ((const float4*)hidden0)[b * 128 + tid];
  __syncthreads();   // xrow ready

  const float4* emb4 = (const float4*)emb;
  if (tid >= 896 && tid < 960) {         // e(0); padding_idx=0 -> zeros
    int idx = xrow[0];
    float4 e0 = make_float4(0.f, 0.f, 0.f, 0.f);
    if (idx != 0) e0 = emb4[idx * (EE / 4) + (tid - 896)];
    comb4[128 + (tid - 896)] = e0;
  }

  // weight preload: rows 128s+4jo+J, cols [24kg, 24kg+24)
  const float4* Wi4 = (const float4*)Wi;
  const size_t rstride = KDIM / 4;
  const float4* wr0 = Wi4 + (size_t)(s * 128 + jo * 4) * rstride + kg * 6;
  const float4* wr1 = wr0 + rstride;
  const float4* wr2 = wr1 + rstride;
  const float4* wr3 = wr2 + rstride;
  FORALL(WLOAD)
  FORALL(WPIN)
  const float bias = (tid < 128) ? bi[s * 128 + tid] : 0.0f;
  __syncthreads();   // comb(0) ready

  unsigned int* cntrow = cnt + b * 16;   // one 64B line per row, slots i&3

  #pragma unroll 1
  for (int i = 0; i < TT; ++i) {
    // ---- FMA phase: 48 pk-FMA/thread, comb via 6 ds_read_b128 ----
    f32x2 acc0 = mk2(0.f, 0.f), acc1 = mk2(0.f, 0.f);
    f32x2 acc2 = mk2(0.f, 0.f), acc3 = mk2(0.f, 0.f);
    const float4* cq = comb4 + kg * 6;
    {
      float4 cc0 = cq[0], cc1 = cq[1], cc2 = cq[2];
      CHUNK1(0) CHUNK1(1) CHUNK1(2) CHUNK1(3)
      float4 cc3 = cq[3], cc4 = cq[4], cc5 = cq[5];
      CHUNK2(0) CHUNK2(1) CHUNK2(2) CHUNK2(3)
    }
    part4[kg * 32 + jo] = make_float4(acc0.x + acc0.y, acc1.x + acc1.y,
                                      acc2.x + acc2.y, acc3.x + acc3.y);
    __syncthreads();   // B1: part ready, comb4 free to overwrite

    const int buf = (i + 1) & 1;
    float* hb = hbuf + (size_t)(buf * BB + b) * HH;

    if (tid < 128) {
      // ---- reduce 32 k-groups, tanh, own slice to LDS + publish ----
      float ssum = bias;
      #pragma unroll
      for (int g = 0; g < 32; ++g) ssum += part[g * 128 + tid];
      float h = fast_tanh(ssum);
      comb[s * 128 + tid] = h;
      if (i != TT - 1) {
        __hip_atomic_store(hb + s * 128 + tid, h, __ATOMIC_RELAXED,
                           __HIP_MEMORY_SCOPE_AGENT);
        asm volatile("s_waitcnt vmcnt(0)" ::: "memory");   // store at IF$
        if ((tid & 63) == 0)
          __hip_atomic_fetch_add(&cntrow[i & 3], 1u, __ATOMIC_RELAXED,
                                 __HIP_MEMORY_SCOPE_AGENT);
      } else {
        hid_out[b * HH + s * 128 + tid] = h;
      }
    } else if (tid >= 512 && i != TT - 1) {
      if (tid < 896) {
        // ---- wait for all 8 publisher waves of this row, fetch foreign ----
        const unsigned target = 8u * ((unsigned)(i >> 2) + 1u);
        while (__hip_atomic_load(&cntrow[i & 3], __ATOMIC_RELAXED,
                                 __HIP_MEMORY_SCOPE_AGENT) < target)
          __builtin_amdgcn_s_sleep(2);
        int r = tid - 512;
        int fj = r + (r >= s * 128 ? 128 : 0);   // skip own 128 j's
        comb[fj] = __hip_atomic_load(hb + fj, __ATOMIC_RELAXED,
                                     __HIP_MEMORY_SCOPE_AGENT);
      } else if (tid < 960) {
        // ---- e(i+1): load hides under the flag round-trip ----
        int idx = xrow[i + 1];
        float4 e4 = make_float4(0.f, 0.f, 0.f, 0.f);
        if (idx != 0) e4 = emb4[idx * (EE / 4) + (tid - 896)];
        comb4[128 + (tid - 896)] = e4;
      }
    }
    __syncthreads();   // B2: comb(i+1) complete
  }
}

// ---------------------------------------------------------------------------
// Decoder: out[b][o] = sum_j h[b][j] * W_dec[o][j] + b_dec[o]
// ---------------------------------------------------------------------------
__global__ __launch_bounds__(256) void dec_kernel(
    const float* __restrict__ hid, const float* __restrict__ Wd,
    const float* __restrict__ bd, float* __restrict__ out)
{
  __shared__ float4 hl4[32 * 128];
  const int o  = blockIdx.x * 256 + threadIdx.x;
  const int b0 = blockIdx.y * 32;

  const float4* hid4 = (const float4*)(hid + b0 * HH);
  #pragma unroll
  for (int i = 0; i < 16; ++i) {
    int lin = i * 256 + threadIdx.x;
    hl4[lin] = hid4[lin];
  }
  __syncthreads();

  f32x2 acc[32];
  #pragma unroll
  for (int bb = 0; bb < 32; ++bb) acc[bb] = mk2(0.f, 0.f);

  const float4* W4 = (const float4*)(Wd + (size_t)o * HH);
  for (int j4 = 0; j4 < 128; ++j4) {
    float4 w = W4[j4];
    f32x2 wa = mk2(w.x, w.y), wb = mk2(w.z, w.w);
    #pragma unroll
    for (int bb = 0; bb < 32; ++bb) {
      float4 h = hl4[bb * 128 + j4];
      acc[bb] = FMA2(wa, mk2(h.x, h.y), acc[bb]);
      acc[bb] = FMA2(wb, mk2(h.z, h.w), acc[bb]);
    }
  }

  const float bias = bd[o];
  #pragma unroll
  for (int bb = 0; bb < 32; ++bb)
    out[(size_t)(b0 + bb) * OO + o] = acc[bb].x + acc[bb].y + bias;
}

// ---------------------------------------------------------------------------
extern "C" void kernel_launch(void* const* d_in, const int* in_sizes, int n_in,
                              void* d_out, int out_size, void* d_ws, size_t ws_size,
                              hipStream_t stream) {
  const int*   x    = (const int*)  d_in[0];   // [64][1024] int32
  const float* hid0 = (const float*)d_in[1];   // [64][512]
  const float* emb  = (const float*)d_in[2];   // [32000][256]
  const float* Wi   = (const float*)d_in[3];   // [512][768]
  const float* bi   = (const float*)d_in[4];   // [512]
  const float* Wd   = (const float*)d_in[5];   // [32000][512]
  const float* bd   = (const float*)d_in[6];   // [32000]

  float* out     = (float*)d_out;              // [64][32000]
  float* hid_out = out + (size_t)BB * OO;      // [64][512] final hidden

  unsigned int* cnt = (unsigned int*)d_ws;                 // [64][16] counters
  float* hbuf = (float*)((char*)d_ws + 8192);              // [2][64][512] f32

  // zero the sync counters every launch (poison/replay-safe; capture-legal)
  hipMemsetAsync(d_ws, 0, 64 * 16 * sizeof(unsigned int), stream);

  rnn_kernel<<<BB * 4, 1024, 0, stream>>>(x, hid0, emb, Wi, bi, hid_out, hbuf, cnt);
  dec_kernel<<<dim3(OO / 256, BB / 32), 256, 0, stream>>>(hid_out, Wd, bd, out);
}

// Round 6
// 1589.614 us; speedup vs baseline: 21.0161x; 1.3939x over previous
//
#include <hip/hip_runtime.h>
#include <math.h>

// Problem dims (fixed by the reference)
#define BB 64
#define TT 1024
#define EE 256
#define HH 512
#define OO 32000
#define KDIM 768   // H+E

typedef float f32x2 __attribute__((ext_vector_type(2)));

__device__ __forceinline__ f32x2 mk2(float a, float b) { f32x2 r; r.x = a; r.y = b; return r; }

#if __has_builtin(__builtin_elementwise_fma)
#define FMA2(a, b, c) __builtin_elementwise_fma((a), (b), (c))
#else
__device__ __forceinline__ f32x2 FMA2(f32x2 a, f32x2 b, f32x2 c) {
  c.x = fmaf(a.x, b.x, c.x); c.y = fmaf(a.y, b.y, c.y); return c;
}
#endif

// fast tanh: (e^2x - 1)/(e^2x + 1); v_exp_f32 is 2^x
__device__ __forceinline__ float fast_tanh(float x) {
  float xc = fminf(fmaxf(x, -10.0f), 10.0f);
  float e;
  asm("v_exp_f32 %0, %1" : "=v"(e) : "v"(xc * 2.885390081777927f)); // 2*log2(e)
  float r;
  asm("v_rcp_f32 %0, %1" : "=v"(r) : "v"(e + 1.0f));
  return (e - 1.0f) * r;
}

// Weight tile: 4 j-rows x 24 k = 96 floats per thread, held as 48 NAMED f32x2
// scalars (no array -> no alloca -> cannot be demoted to scratch).
#define FORQ(M, J) M(J,0) M(J,1) M(J,2) M(J,3) M(J,4) M(J,5)
#define FORALL(M) FORQ(M,0) FORQ(M,1) FORQ(M,2) FORQ(M,3)

#define WLOAD(J,Q) float4 v##J##_##Q = wr##J[Q]; \
  f32x2 wa##J##_##Q = mk2(v##J##_##Q.x, v##J##_##Q.y); \
  f32x2 wb##J##_##Q = mk2(v##J##_##Q.z, v##J##_##Q.w);
#define WPIN(J,Q) asm volatile("" : "+v"(wa##J##_##Q), "+v"(wb##J##_##Q));
#define WFMA(J,Q) acc##J = FMA2(wa##J##_##Q, mk2(cc##Q.x, cc##Q.y), acc##J); \
                  acc##J = FMA2(wb##J##_##Q, mk2(cc##Q.z, cc##Q.w), acc##J);
#define CHUNK1(J) WFMA(J,0) WFMA(J,1) WFMA(J,2)
#define CHUNK2(J) WFMA(J,3) WFMA(J,4) WFMA(J,5)

// ---------------------------------------------------------------------------
// Recurrence: 256 blocks (1/CU), 1024 threads. bid -> b = bid&63, s = bid>>6.
// Block owns output rows j in [128s, 128s+128), all k. Thread: jo = tid&31
// (4 j-rows 128s+4jo..+3), kg = tid>>5 (k-slice [24kg, 24kg+24)).
// Cross-block exchange: TAGGED DATA. Publisher stores one atomic 8-byte
// {f32 h, u32 tag=i+1} per hidden value (agent-scope relaxed, dwordx2 —
// single-copy atomic). Readers poll their own word until tag==i+1: no flag
// round-trip, no vmcnt(0) drain, no contended fetch_adds (R4's ~2500-cycle
// serialization deleted). Double-buffer parity + per-step end barrier bound
// the skew to <2 steps, so slots are never overwritten before consumption.
// hbuf tags are zeroed every launch (graph replays repeat the tag sequence).
// ---------------------------------------------------------------------------
__global__ __launch_bounds__(1024, 4) void rnn_kernel(
    const int* __restrict__ x, const float* __restrict__ hidden0,
    const float* __restrict__ emb, const float* __restrict__ Wi,
    const float* __restrict__ bi, float* __restrict__ hid_out,
    unsigned long long* __restrict__ hbuf)
{
  __shared__ float4 comb4[KDIM / 4];   // [0..127]=h (global j), [128..191]=e
  __shared__ float4 part4[32 * 32];    // [kg=32][j=128]
  __shared__ int xrow[TT];
  float* comb = (float*)comb4;
  float* part = (float*)part4;

  const int bid = blockIdx.x;
  const int b = bid & 63, s = bid >> 6;
  const int tid = threadIdx.x;
  const int jo = tid & 31;
  const int kg = tid >> 5;

  xrow[tid] = x[b * TT + tid];
  if (tid < 128) comb4[tid] = ((const float4*)hidden0)[b * 128 + tid];

  const float4* emb4 = (const float4*)emb;
  if (tid >= 896 && tid < 960) {       // e(0); padding_idx=0 -> zeros
    int idx = x[b * TT];
    float4 e0 = make_float4(0.f, 0.f, 0.f, 0.f);
    if (idx != 0) e0 = emb4[idx * (EE / 4) + (tid - 896)];
    comb4[128 + (tid - 896)] = e0;
  }

  // weight preload: rows 128s+4jo+J, cols [24kg, 24kg+24)
  const float4* Wi4 = (const float4*)Wi;
  const size_t rstride = KDIM / 4;
  const float4* wr0 = Wi4 + (size_t)(s * 128 + jo * 4) * rstride + kg * 6;
  const float4* wr1 = wr0 + rstride;
  const float4* wr2 = wr1 + rstride;
  const float4* wr3 = wr2 + rstride;
  FORALL(WLOAD)
  FORALL(WPIN)
  const float bias = (tid < 128) ? bi[s * 128 + tid] : 0.0f;
  __syncthreads();   // comb(0), xrow, weights ready

  const int last = TT - 1;

  #pragma unroll 1
  for (int i = 0; i < TT; ++i) {
    // -------- phase X: FMA over comb(i) --------
    f32x2 acc0 = mk2(0.f, 0.f), acc1 = mk2(0.f, 0.f);
    f32x2 acc2 = mk2(0.f, 0.f), acc3 = mk2(0.f, 0.f);
    const float4* cq = comb4 + kg * 6;
    {
      float4 cc0 = cq[0], cc1 = cq[1], cc2 = cq[2];
      CHUNK1(0) CHUNK1(1) CHUNK1(2) CHUNK1(3)
      float4 cc3 = cq[3], cc4 = cq[4], cc5 = cq[5];
      CHUNK2(0) CHUNK2(1) CHUNK2(2) CHUNK2(3)
    }
    part4[kg * 32 + jo] = make_float4(acc0.x + acc0.y, acc1.x + acc1.y,
                                      acc2.x + acc2.y, acc3.x + acc3.y);
    __syncthreads();   // B1: part(i) ready; comb free for step i+1 data

    // -------- phase Y: produce comb(i+1) --------
    const int par = (i + 1) & 1;
    unsigned long long* hb = hbuf + (size_t)(par * BB + b) * HH;

    if (tid < 128) {
      // reduce 32 k-groups, tanh, publish tagged, own slice -> LDS
      float ssum = bias;
      #pragma unroll
      for (int g = 0; g < 32; ++g) ssum += part[g * 128 + tid];
      float h = fast_tanh(ssum);
      if (i == last) {
        hid_out[b * HH + s * 128 + tid] = h;
      } else {
        unsigned long long pv =
            ((unsigned long long)(unsigned)(i + 1) << 32) | __float_as_uint(h);
        __hip_atomic_store(hb + s * 128 + tid, pv, __ATOMIC_RELAXED,
                           __HIP_MEMORY_SCOPE_AGENT);   // fire-and-forget
      }
      comb[s * 128 + tid] = h;
    } else if (tid >= 512 && i != last) {
      if (tid < 896) {
        // poll own foreign word until its step tag arrives
        int r = tid - 512;
        int fj = r + (r >= s * 128 ? 128 : 0);   // skip own 128 j's
        const unsigned tgt = (unsigned)(i + 1);
        unsigned long long v;
        do {
          v = __hip_atomic_load(hb + fj, __ATOMIC_RELAXED,
                                __HIP_MEMORY_SCOPE_AGENT);
        } while ((unsigned)(v >> 32) < tgt);
        comb[fj] = __uint_as_float((unsigned)v);
      } else if (tid < 960) {
        // e(i+1): load hides under the sibling poll window
        int idx = xrow[i + 1];
        float4 e4 = make_float4(0.f, 0.f, 0.f, 0.f);
        if (idx != 0) e4 = emb4[idx * (EE / 4) + (tid - 896)];
        comb4[128 + (tid - 896)] = e4;
      }
    }
    __syncthreads();   // B2: comb(i+1) complete
  }
}

// ---------------------------------------------------------------------------
// Decoder: out[b][o] = sum_j h[b][j] * W_dec[o][j] + b_dec[o]
// ---------------------------------------------------------------------------
__global__ __launch_bounds__(256) void dec_kernel(
    const float* __restrict__ hid, const float* __restrict__ Wd,
    const float* __restrict__ bd, float* __restrict__ out)
{
  __shared__ float4 hl4[32 * 128];
  const int o  = blockIdx.x * 256 + threadIdx.x;
  const int b0 = blockIdx.y * 32;

  const float4* hid4 = (const float4*)(hid + b0 * HH);
  #pragma unroll
  for (int i = 0; i < 16; ++i) {
    int lin = i * 256 + threadIdx.x;
    hl4[lin] = hid4[lin];
  }
  __syncthreads();

  f32x2 acc[32];
  #pragma unroll
  for (int bb = 0; bb < 32; ++bb) acc[bb] = mk2(0.f, 0.f);

  const float4* W4 = (const float4*)(Wd + (size_t)o * HH);
  for (int j4 = 0; j4 < 128; ++j4) {
    float4 w = W4[j4];
    f32x2 wa = mk2(w.x, w.y), wb = mk2(w.z, w.w);
    #pragma unroll
    for (int bb = 0; bb < 32; ++bb) {
      float4 h = hl4[bb * 128 + j4];
      acc[bb] = FMA2(wa, mk2(h.x, h.y), acc[bb]);
      acc[bb] = FMA2(wb, mk2(h.z, h.w), acc[bb]);
    }
  }

  const float bias = bd[o];
  #pragma unroll
  for (int bb = 0; bb < 32; ++bb)
    out[(size_t)(b0 + bb) * OO + o] = acc[bb].x + acc[bb].y + bias;
}

// ---------------------------------------------------------------------------
extern "C" void kernel_launch(void* const* d_in, const int* in_sizes, int n_in,
                              void* d_out, int out_size, void* d_ws, size_t ws_size,
                              hipStream_t stream) {
  const int*   x    = (const int*)  d_in[0];   // [64][1024] int32
  const float* hid0 = (const float*)d_in[1];   // [64][512]
  const float* emb  = (const float*)d_in[2];   // [32000][256]
  const float* Wi   = (const float*)d_in[3];   // [512][768]
  const float* bi   = (const float*)d_in[4];   // [512]
  const float* Wd   = (const float*)d_in[5];   // [32000][512]
  const float* bd   = (const float*)d_in[6];   // [32000]

  float* out     = (float*)d_out;              // [64][32000]
  float* hid_out = out + (size_t)BB * OO;      // [64][512] final hidden

  unsigned long long* hbuf = (unsigned long long*)d_ws;    // [2][64][512] x 8B

  // zero all tags every launch: graph replays repeat the same tag sequence,
  // so stale tags from the previous replay would alias (capture-legal memset)
  hipMemsetAsync(d_ws, 0, (size_t)2 * BB * HH * sizeof(unsigned long long),
                 stream);

  rnn_kernel<<<BB * 4, 1024, 0, stream>>>(x, hid0, emb, Wi, bi, hid_out, hbuf);
  dec_kernel<<<dim3(OO / 256, BB / 32), 256, 0, stream>>>(hid_out, Wd, bd, out);
}